// Round 9
// baseline (210.943 us; speedup 1.0000x reference)
//
#include <hip/hip_runtime.h>
#include <hip/hip_bf16.h>

typedef __attribute__((ext_vector_type(8))) short bf16x8;
typedef __attribute__((ext_vector_type(4))) float f32x4;
typedef unsigned short u16;

constexpr int NSEQ = 16384;
constexpr int KD   = 4096;
constexpr int NQ   = 512;     // q cols
constexpr int NCOL = 640;     // q (512) + k (128)
constexpr int BM   = 128;
constexpr int BK   = 32;
constexpr int KHALF = 2048;
constexpr int NKS  = KHALF / BK;          // 64 K-steps per block
// Wst layout: [kh(2)][tt(64)][nblk(8)][frag i(5)][lane(64)][e(8)] u16
constexpr int WST_PER_KH = 64 * 8 * 5 * 64 * 8;   // 1,310,720 u16
constexpr int WST_TT     = 8 * 5 * 64 * 8;        // 20480 u16
constexpr int WST_NB     = 5 * 64 * 8;            // 2560 u16
constexpr int WCONV_THREADS = 2 * 64 * 8 * 5 * 64;   // 327,680

// ---- f32 -> bf16 (RTNE) pack helpers -------------------------------------
__device__ __forceinline__ unsigned bf_round(float x) {
    unsigned u = __builtin_bit_cast(unsigned, x);
    unsigned r = u + 0x7FFFu + ((u >> 16) & 1u);
    return r >> 16;
}
__device__ __forceinline__ unsigned pk2(float lo, float hi) {
    return bf_round(lo) | (bf_round(hi) << 16);
}
__device__ __forceinline__ float bfu(unsigned u) {
    return __builtin_bit_cast(float, u << 16);
}

// ---- Kernel 1: W (q_w ++ k_w) f32 -> bf16, per-(step,wave) fragment blocks
__global__ __launch_bounds__(256) void wconv_kernel(
    const float* __restrict__ qw, const float* __restrict__ kw,
    u16* __restrict__ Wst)
{
    int g = blockIdx.x * 256 + threadIdx.x;
    int lane = g & 63;
    int r  = g >> 6;
    int i  = r % 5;  r /= 5;
    int nblk = r & 7;  r >>= 3;
    int tt = r & 63;
    int kh = r >> 6;
    int n  = nblk * 80 + i * 16 + (lane & 15);
    int k0 = kh * KHALF + tt * BK + ((lane >> 4) << 3);
    const float* src = (n < NQ) ? (qw + (size_t)n * KD + k0)
                                : (kw + (size_t)(n - NQ) * KD + k0);
    float4 v0 = *(const float4*)(src);
    float4 v1 = *(const float4*)(src + 4);
    int4 o;
    o.x = (int)pk2(v0.x, v0.y);
    o.y = (int)pk2(v0.z, v0.w);
    o.z = (int)pk2(v1.x, v1.y);
    o.w = (int)pk2(v1.z, v1.w);
    *(int4*)(Wst + (size_t)g * 8) = o;
}

// ---- Kernel 2: K-split GEMM, B global->reg, A in 8-step LDS windows ------
// grid 256; XCD b&7 owns K-half (b&7)&1. 8 waves = 8 N-slices of 80 cols;
// wave tile 128 x 80, acc[8][5]. Barrier ONCE per 8-step window (8 total):
// within a window no barriers/waitcnt -> compiler pipelines B-loads and
// ds_reads across steps; co-resident waves drift to hide L2 latency.
// A staged per window (64KB bf16, double-buffered 128KB LDS) with depth-2
// reg rotation: at step tt write A(tt+8), load A(tt+9).
__global__ __launch_bounds__(512, 2) void gemm_kernel(
    const float* __restrict__ hid, const u16* __restrict__ Wst,
    u16* __restrict__ P0, u16* __restrict__ P1)
{
    __shared__ __align__(16) char smem[2 * 8 * 8192];   // 128 KB

    const int t    = threadIdx.x;
    const int lane = t & 63;
    const int wid  = t >> 6;        // 0..7 = N-slice

    const int b    = blockIdx.x;
    const int xcd  = b & 7;
    const int kh   = xcd & 1;
    const int mblk = (b >> 3) * 4 + (xcd >> 1);   // 0..127, bijective
    const int row0 = mblk * BM;

    const float* hk = hid + (size_t)row0 * KD + kh * KHALF;
    const u16*   wb = Wst + (size_t)kh * WST_PER_KH + wid * WST_NB + lane * 8;
    u16* P = kh ? P1 : P0;

    f32x4 acc[8][5] = {};

    // A staging: thread t -> row ar (0..127), k-slot ks8 (0..3), 8 f32
    const int ar  = t >> 2;
    const int ks8 = t & 3;
    const float* gA = hk + (size_t)ar * KD + ks8 * 8;
    const int aWoff = ar * 64 + ((ks8 ^ ((ar >> 1) & 3)) << 4);

    // A fragment read params (XOR-swizzled k-slot, 0-conflict proven)
    const int bn   = lane & 15;
    const int koff = (((lane >> 4) ^ ((bn >> 1) & 3)) << 4);

    float4 p0a, p0b, p1a, p1b;

    // ---- prologue: stage window 0 (slots 0..7), preload A(8) ----
    #pragma unroll
    for (int s = 0; s < 8; ++s) {
        float4 va = *(const float4*)(gA + s * BK);
        float4 vb = *(const float4*)(gA + s * BK + 4);
        int4 ap_;
        ap_.x = (int)pk2(va.x, va.y);  ap_.y = (int)pk2(va.z, va.w);
        ap_.z = (int)pk2(vb.x, vb.y);  ap_.w = (int)pk2(vb.z, vb.w);
        *(int4*)(smem + s * 8192 + aWoff) = ap_;
    }
    p0a = *(const float4*)(gA + 8 * BK);
    p0b = *(const float4*)(gA + 8 * BK + 4);
    asm volatile("s_waitcnt lgkmcnt(0)" ::: "memory");
    __builtin_amdgcn_s_barrier();
    asm volatile("" ::: "memory");

#define WSTEP(S, PWa, PWb, PLa, PLb)                                             \
    {                                                                            \
        if (stg) {                                                               \
            int4 ap_;                                                            \
            ap_.x = (int)pk2(PWa.x, PWa.y);  ap_.y = (int)pk2(PWa.z, PWa.w);     \
            ap_.z = (int)pk2(PWb.x, PWb.y);  ap_.w = (int)pk2(PWb.z, PWb.w);     \
            *(int4*)(nbase + (S) * 8192 + aWoff) = ap_;                          \
            if (full || (S) < 7) {                                               \
                PLa = *(const float4*)(gAw + ((S) + 9) * BK);                    \
                PLb = *(const float4*)(gAw + ((S) + 9) * BK + 4);                \
            }                                                                    \
        }                                                                        \
        const u16* wp = wpw + (S) * WST_TT;                                      \
        bf16x8 bf0 = *(const bf16x8*)(wp);                                       \
        bf16x8 bf1 = *(const bf16x8*)(wp + 512);                                 \
        bf16x8 bf2 = *(const bf16x8*)(wp + 1024);                                \
        bf16x8 bf3 = *(const bf16x8*)(wp + 1536);                                \
        bf16x8 bf4 = *(const bf16x8*)(wp + 2048);                                \
        const char* sAc = cbase + (S) * 8192;                                    \
        _Pragma("unroll")                                                        \
        for (int m = 0; m < 8; ++m) {                                            \
            bf16x8 a_ = *(const bf16x8*)(sAc + (m * 16 + bn) * 64 + koff);       \
            acc[m][0] = __builtin_amdgcn_mfma_f32_16x16x32_bf16(a_, bf0, acc[m][0], 0, 0, 0); \
            acc[m][1] = __builtin_amdgcn_mfma_f32_16x16x32_bf16(a_, bf1, acc[m][1], 0, 0, 0); \
            acc[m][2] = __builtin_amdgcn_mfma_f32_16x16x32_bf16(a_, bf2, acc[m][2], 0, 0, 0); \
            acc[m][3] = __builtin_amdgcn_mfma_f32_16x16x32_bf16(a_, bf3, acc[m][3], 0, 0, 0); \
            acc[m][4] = __builtin_amdgcn_mfma_f32_16x16x32_bf16(a_, bf4, acc[m][4], 0, 0, 0); \
        }                                                                        \
    }

    // ---- steady: 8 windows x 8 steps, one barrier per window ----
#pragma unroll 1
    for (int w = 0; w < 8; ++w) {
        const char* cbase = smem + (w & 1) * 65536;
        char*       nbase = smem + ((w & 1) ^ 1) * 65536;
        const u16*  wpw   = wb + (size_t)(w * 8) * WST_TT;
        const float* gAw  = gA + (w * 8) * BK;
        const bool stg  = (w < 7);
        const bool full = (w < 6);
        WSTEP(0, p0a, p0b, p1a, p1b)
        WSTEP(1, p1a, p1b, p0a, p0b)
        WSTEP(2, p0a, p0b, p1a, p1b)
        WSTEP(3, p1a, p1b, p0a, p0b)
        WSTEP(4, p0a, p0b, p1a, p1b)
        WSTEP(5, p1a, p1b, p0a, p0b)
        WSTEP(6, p0a, p0b, p1a, p1b)
        WSTEP(7, p1a, p1b, p0a, p0b)
        asm volatile("s_waitcnt lgkmcnt(0)" ::: "memory");
        __builtin_amdgcn_s_barrier();
        asm volatile("" ::: "memory");
    }
#undef WSTEP

    // epilogue: bf16 partial-P write. C/D: col=lane&15, row=(lane>>4)*4+j
    const int crow = (lane >> 4) << 2;
    const int ccol = lane & 15;
    #pragma unroll
    for (int m = 0; m < 8; ++m)
        #pragma unroll
        for (int f = 0; f < 5; ++f)
            #pragma unroll
            for (int j = 0; j < 4; ++j)
                P[(size_t)(row0 + m * 16 + crow + j) * NCOL
                  + wid * 80 + f * 16 + ccol] = (u16)bf_round(acc[m][f][j]);
}

// ---- Kernel 3: gating epilogue (reads two bf16 partial-P halves) ----------
__global__ __launch_bounds__(256) void gate_kernel(
    const u16* __restrict__ P0, const u16* __restrict__ P1,
    const float* __restrict__ qb,
    const float* __restrict__ qnw, const float* __restrict__ knw,
    const float* __restrict__ kbase, const float* __restrict__ bb,
    float* __restrict__ out)
{
    __shared__ float skb[8 * 16 * 16];
    __shared__ float sqb[512];
    __shared__ float sb[32];
    __shared__ float snw[32];

    int tid = threadIdx.x;
    for (int i = tid; i < 2048; i += 256) skb[i] = kbase[i];
    for (int i = tid; i < 512;  i += 256) sqb[i] = qb[i];
    if (tid < 32) sb[tid] = bb[tid];
    if (tid < 16) snw[tid] = qnw[tid];
    else if (tid < 32) snw[tid] = knw[tid - 16];
    __syncthreads();

    int gid = blockIdx.x * 256 + tid;
    int tok = gid >> 5;
    int hh  = (gid >> 2) & 7;
    int g   = gid & 3;

    const u16* r0 = P0 + (size_t)tok * NCOL;
    const u16* r1 = P1 + (size_t)tok * NCOL;
    const int qoff = (hh * 4 + g) * 16;

    // q row = P0 + P1 + bias, then RMSNorm
    float q[16];
    float ss = 0.f;
    {
        int4 a0 = *(const int4*)(r0 + qoff);
        int4 a1 = *(const int4*)(r0 + qoff + 8);
        int4 b0 = *(const int4*)(r1 + qoff);
        int4 b1 = *(const int4*)(r1 + qoff + 8);
        int wa[8] = {a0.x, a0.y, a0.z, a0.w, a1.x, a1.y, a1.z, a1.w};
        int wb[8] = {b0.x, b0.y, b0.z, b0.w, b1.x, b1.y, b1.z, b1.w};
        #pragma unroll
        for (int i = 0; i < 8; ++i) {
            unsigned ua = (unsigned)wa[i], ub = (unsigned)wb[i];
            q[2*i+0] = bfu(ua & 0xFFFFu) + bfu(ub & 0xFFFFu) + sqb[qoff + 2*i+0];
            q[2*i+1] = bfu(ua >> 16)     + bfu(ub >> 16)     + sqb[qoff + 2*i+1];
        }
        #pragma unroll
        for (int d = 0; d < 16; ++d) ss += q[d] * q[d];
    }
    float rq = rsqrtf(ss * (1.f / 16.f) + 1e-6f);
    #pragma unroll
    for (int d = 0; d < 16; ++d) q[d] *= rq * snw[d];

    // k row, RMSNorm
    float k[16];
    float sk = 0.f;
    {
        const int koffb = NQ + hh * 16;
        int4 a0 = *(const int4*)(r0 + koffb);
        int4 a1 = *(const int4*)(r0 + koffb + 8);
        int4 b0 = *(const int4*)(r1 + koffb);
        int4 b1 = *(const int4*)(r1 + koffb + 8);
        int wa[8] = {a0.x, a0.y, a0.z, a0.w, a1.x, a1.y, a1.z, a1.w};
        int wb[8] = {b0.x, b0.y, b0.z, b0.w, b1.x, b1.y, b1.z, b1.w};
        #pragma unroll
        for (int i = 0; i < 8; ++i) {
            unsigned ua = (unsigned)wa[i], ub = (unsigned)wb[i];
            k[2*i+0] = bfu(ua & 0xFFFFu) + bfu(ub & 0xFFFFu);
            k[2*i+1] = bfu(ua >> 16)     + bfu(ub >> 16);
        }
        #pragma unroll
        for (int d = 0; d < 16; ++d) sk += k[d] * k[d];
    }
    float rk = rsqrtf(sk * (1.f / 16.f) + 1e-6f);

    // logit = k̂·q̂ / 4 + b
    float logit = 0.f;
    #pragma unroll
    for (int d = 0; d < 16; ++d) logit += (k[d] * rk * snw[16 + d]) * q[d];
    logit = logit * 0.25f + sb[hh * 4 + g];

    // sum over sink tokens
    float accum = 0.f;
    const float* kbh = skb + hh * 256;
    #pragma unroll
    for (int s = 0; s < 16; ++s) {
        float lb = 0.f;
        #pragma unroll
        for (int d = 0; d < 16; ++d) lb += kbh[s * 16 + d] * q[d];
        accum += __expf(lb * 0.25f - logit);
    }
    float r = 1.f / (1.f + accum);

    // mean over g (4 lanes), lane g==0 writes
    r += __shfl_xor(r, 1);
    r += __shfl_xor(r, 2);
    if (g == 0) out[(size_t)hh * NSEQ + tok] = r * 0.25f;
}

// ---- launch ---------------------------------------------------------------
extern "C" void kernel_launch(void* const* d_in, const int* in_sizes, int n_in,
                              void* d_out, int out_size, void* d_ws, size_t ws_size,
                              hipStream_t stream)
{
    const float* hid = (const float*)d_in[0];
    const float* qw  = (const float*)d_in[1];
    const float* qb  = (const float*)d_in[2];
    const float* kw  = (const float*)d_in[3];
    const float* qnw = (const float*)d_in[4];
    const float* knw = (const float*)d_in[5];
    const float* kb  = (const float*)d_in[6];
    const float* bb  = (const float*)d_in[7];
    float* out = (float*)d_out;

    u16* Wst = (u16*)d_ws;                                        // 5,242,880 B
    u16* P0  = (u16*)((char*)d_ws + (size_t)NCOL * KD * 2);       // 20,971,520 B
    u16* P1  = P0 + (size_t)NSEQ * NCOL;                          // 20,971,520 B

    wconv_kernel<<<WCONV_THREADS / 256, 256, 0, stream>>>(qw, kw, Wst);
    gemm_kernel<<<256, 512, 0, stream>>>(hid, Wst, P0, P1);
    gate_kernel<<<NSEQ * 32 / 256, 256, 0, stream>>>(P0, P1, qb, qnw, knw, kb, bb, out);
}

// Round 10
// 158.726 us; speedup vs baseline: 1.3290x; 1.3290x over previous
//
#include <hip/hip_runtime.h>
#include <hip/hip_bf16.h>

typedef __attribute__((ext_vector_type(8))) short bf16x8;
typedef __attribute__((ext_vector_type(4))) float f32x4;
typedef unsigned short u16;

constexpr int NSEQ = 16384;
constexpr int KD   = 4096;
constexpr int NQ   = 512;     // q cols
constexpr int NCOL = 640;     // q (512) + k (128)
constexpr int BM   = 64;
constexpr int BK   = 32;
constexpr int KHALF = 2048;
constexpr int NKS  = KHALF / BK;          // 64 K-steps per block
// Wst layout: [kh(2)][tt(64)][nblk(8)][frag i(5)][lane(64)][e(8)] u16
constexpr int WST_PER_KH = 64 * 8 * 5 * 64 * 8;   // 1,310,720 u16
constexpr int WST_TT     = 8 * 5 * 64 * 8;        // 20480 u16
constexpr int WST_NB     = 5 * 64 * 8;            // 2560 u16
constexpr int WCONV_THREADS = 2 * 64 * 8 * 5 * 64;   // 327,680

// ---- f32 -> bf16 (RTNE) pack helpers -------------------------------------
__device__ __forceinline__ unsigned bf_round(float x) {
    unsigned u = __builtin_bit_cast(unsigned, x);
    unsigned r = u + 0x7FFFu + ((u >> 16) & 1u);
    return r >> 16;
}
__device__ __forceinline__ unsigned pk2(float lo, float hi) {
    return bf_round(lo) | (bf_round(hi) << 16);
}
__device__ __forceinline__ float bfu(unsigned u) {
    return __builtin_bit_cast(float, u << 16);
}

// ---- Kernel 1: W (q_w ++ k_w) f32 -> bf16, per-(step,wave) fragment blocks
// (identical to R8 — proven)
__global__ __launch_bounds__(256) void wconv_kernel(
    const float* __restrict__ qw, const float* __restrict__ kw,
    u16* __restrict__ Wst)
{
    int g = blockIdx.x * 256 + threadIdx.x;
    int lane = g & 63;
    int r  = g >> 6;
    int i  = r % 5;  r /= 5;
    int nblk = r & 7;  r >>= 3;
    int tt = r & 63;
    int kh = r >> 6;
    int n  = nblk * 80 + i * 16 + (lane & 15);
    int k0 = kh * KHALF + tt * BK + ((lane >> 4) << 3);
    const float* src = (n < NQ) ? (qw + (size_t)n * KD + k0)
                                : (kw + (size_t)(n - NQ) * KD + k0);
    float4 v0 = *(const float4*)(src);
    float4 v1 = *(const float4*)(src + 4);
    int4 o;
    o.x = (int)pk2(v0.x, v0.y);
    o.y = (int)pk2(v0.z, v0.w);
    o.z = (int)pk2(v1.x, v1.y);
    o.w = (int)pk2(v1.z, v1.w);
    *(int4*)(Wst + (size_t)g * 8) = o;
}

// ---- Kernel 2: K-split GEMM, B global->reg, 2 blocks/CU -------------------
// grid 512 = 256 M-blocks x 2 kh; XCD b&7 owns kh (b&7)&1 -> co-resident
// blocks share the W stream (L1/L2 reuse). BM=64, 512 threads = 8 waves,
// wave tile 64 x 80 (acc[4][5]). Per K-step (R8 structure): 5 B-frag plain
// loads -> VGPR, 1 float4 A-prefetch (depth 2), 8B A ds_write, 4 A-frag
// ds_reads, 20 MFMA, lgkm(0)+barrier. Two barrier-groups per CU overlap.
__global__ __launch_bounds__(512, 4) void gemm_kernel(
    const float* __restrict__ hid, const u16* __restrict__ Wst,
    u16* __restrict__ P0, u16* __restrict__ P1)
{
    __shared__ __align__(16) char smem[2 * 4096];   // A double-buffer, 8 KB

    const int t    = threadIdx.x;
    const int lane = t & 63;
    const int wid  = t >> 6;        // 0..7 = N-slice of 80 cols

    const int b    = blockIdx.x;
    const int xcd  = b & 7;
    const int kh   = xcd & 1;
    const int mblk = (b >> 3) * 4 + (xcd >> 1);   // 0..255, bijective
    const int row0 = mblk * BM;

    const float* hk = hid + (size_t)row0 * KD + kh * KHALF;
    const u16*   wb = Wst + (size_t)kh * WST_PER_KH + wid * WST_NB + lane * 8;
    u16* P = kh ? P1 : P0;

    f32x4 acc[4][5] = {};

    // A staging: thread t -> row ar (0..63), slot ks4 (0..7, 4 f32 each)
    const int ar  = t >> 3;
    const int ks4 = t & 7;
    const float* gA = hk + (size_t)ar * KD + ks4 * 4;
    const int aWoff = ar * 64 + ((((ks4 >> 1) ^ ((ar >> 1) & 3)) << 4)
                                 + (ks4 & 1) * 8);

    // A fragment read params (XOR-swizzled 16B k-slots, 0-conflict proven)
    const int bn   = lane & 15;
    const int koff = (((lane >> 4) ^ ((bn >> 1) & 3)) << 4);

    float4 s0, s1;

#define STEPX(TT, CUR, SW, SL, HG, HA)                                           \
    {                                                                            \
        const u16* wp = wb + (size_t)(TT) * WST_TT;                              \
        bf16x8 bf0 = *(const bf16x8*)(wp);                                       \
        bf16x8 bf1 = *(const bf16x8*)(wp + 512);                                 \
        bf16x8 bf2 = *(const bf16x8*)(wp + 1024);                                \
        bf16x8 bf3 = *(const bf16x8*)(wp + 1536);                                \
        bf16x8 bf4 = *(const bf16x8*)(wp + 2048);                                \
        if (HA) { SL = *(const float4*)(gA + ((TT) + 2) * BK); }                 \
        if (HG) {                                                                \
            int2 ap_;                                                            \
            ap_.x = (int)pk2(SW.x, SW.y);                                        \
            ap_.y = (int)pk2(SW.z, SW.w);                                        \
            *(int2*)(smem + ((CUR) ^ 1) * 4096 + aWoff) = ap_;                   \
        }                                                                        \
        const char* sAc = smem + (CUR) * 4096;                                   \
        _Pragma("unroll")                                                        \
        for (int m = 0; m < 4; ++m) {                                            \
            bf16x8 a_ = *(const bf16x8*)(sAc + (m * 16 + bn) * 64 + koff);       \
            acc[m][0] = __builtin_amdgcn_mfma_f32_16x16x32_bf16(a_, bf0, acc[m][0], 0, 0, 0); \
            acc[m][1] = __builtin_amdgcn_mfma_f32_16x16x32_bf16(a_, bf1, acc[m][1], 0, 0, 0); \
            acc[m][2] = __builtin_amdgcn_mfma_f32_16x16x32_bf16(a_, bf2, acc[m][2], 0, 0, 0); \
            acc[m][3] = __builtin_amdgcn_mfma_f32_16x16x32_bf16(a_, bf3, acc[m][3], 0, 0, 0); \
            acc[m][4] = __builtin_amdgcn_mfma_f32_16x16x32_bf16(a_, bf4, acc[m][4], 0, 0, 0); \
        }                                                                        \
        asm volatile("s_waitcnt lgkmcnt(0)" ::: "memory");                       \
        __builtin_amdgcn_s_barrier();                                            \
    }

    // ---- prologue: s0=A(0), s1=A(1); write A(0)->buf0; barrier ----
    s0 = *(const float4*)(gA);
    s1 = *(const float4*)(gA + BK);
    {
        int2 ap_;
        ap_.x = (int)pk2(s0.x, s0.y);
        ap_.y = (int)pk2(s0.z, s0.w);
        *(int2*)(smem + aWoff) = ap_;
    }
    asm volatile("s_waitcnt lgkmcnt(0)" ::: "memory");
    __builtin_amdgcn_s_barrier();

    // ---- steady: tt = 0..61 ----
#pragma unroll 1
    for (int t2 = 0; t2 < 31; ++t2) {
        const int tt = t2 * 2;
        STEPX(tt,     0, s1, s0, 1, 1)   // write A(tt+1)->buf1, load A(tt+2)
        STEPX(tt + 1, 1, s0, s1, 1, 1)   // write A(tt+2)->buf0, load A(tt+3)
    }
    // ---- tail ----
    STEPX(62, 0, s1, s0, 1, 0)   // write A(63)->buf1
    STEPX(63, 1, s0, s1, 0, 0)   // pure compute
#undef STEPX

    // epilogue: bf16 partial-P write. C/D: col=lane&15, row=(lane>>4)*4+j
    const int crow = (lane >> 4) << 2;
    const int ccol = lane & 15;
    #pragma unroll
    for (int m = 0; m < 4; ++m)
        #pragma unroll
        for (int f = 0; f < 5; ++f)
            #pragma unroll
            for (int j = 0; j < 4; ++j)
                P[(size_t)(row0 + m * 16 + crow + j) * NCOL
                  + wid * 80 + f * 16 + ccol] = (u16)bf_round(acc[m][f][j]);
}

// ---- Kernel 3: gating epilogue (reads two bf16 partial-P halves) ----------
__global__ __launch_bounds__(256) void gate_kernel(
    const u16* __restrict__ P0, const u16* __restrict__ P1,
    const float* __restrict__ qb,
    const float* __restrict__ qnw, const float* __restrict__ knw,
    const float* __restrict__ kbase, const float* __restrict__ bb,
    float* __restrict__ out)
{
    __shared__ float skb[8 * 16 * 16];
    __shared__ float sqb[512];
    __shared__ float sb[32];
    __shared__ float snw[32];

    int tid = threadIdx.x;
    for (int i = tid; i < 2048; i += 256) skb[i] = kbase[i];
    for (int i = tid; i < 512;  i += 256) sqb[i] = qb[i];
    if (tid < 32) sb[tid] = bb[tid];
    if (tid < 16) snw[tid] = qnw[tid];
    else if (tid < 32) snw[tid] = knw[tid - 16];
    __syncthreads();

    int gid = blockIdx.x * 256 + tid;
    int tok = gid >> 5;
    int hh  = (gid >> 2) & 7;
    int g   = gid & 3;

    const u16* r0 = P0 + (size_t)tok * NCOL;
    const u16* r1 = P1 + (size_t)tok * NCOL;
    const int qoff = (hh * 4 + g) * 16;

    // q row = P0 + P1 + bias, then RMSNorm
    float q[16];
    float ss = 0.f;
    {
        int4 a0 = *(const int4*)(r0 + qoff);
        int4 a1 = *(const int4*)(r0 + qoff + 8);
        int4 b0 = *(const int4*)(r1 + qoff);
        int4 b1 = *(const int4*)(r1 + qoff + 8);
        int wa[8] = {a0.x, a0.y, a0.z, a0.w, a1.x, a1.y, a1.z, a1.w};
        int wb[8] = {b0.x, b0.y, b0.z, b0.w, b1.x, b1.y, b1.z, b1.w};
        #pragma unroll
        for (int i = 0; i < 8; ++i) {
            unsigned ua = (unsigned)wa[i], ub = (unsigned)wb[i];
            q[2*i+0] = bfu(ua & 0xFFFFu) + bfu(ub & 0xFFFFu) + sqb[qoff + 2*i+0];
            q[2*i+1] = bfu(ua >> 16)     + bfu(ub >> 16)     + sqb[qoff + 2*i+1];
        }
        #pragma unroll
        for (int d = 0; d < 16; ++d) ss += q[d] * q[d];
    }
    float rq = rsqrtf(ss * (1.f / 16.f) + 1e-6f);
    #pragma unroll
    for (int d = 0; d < 16; ++d) q[d] *= rq * snw[d];

    // k row, RMSNorm
    float k[16];
    float sk = 0.f;
    {
        const int koffb = NQ + hh * 16;
        int4 a0 = *(const int4*)(r0 + koffb);
        int4 a1 = *(const int4*)(r0 + koffb + 8);
        int4 b0 = *(const int4*)(r1 + koffb);
        int4 b1 = *(const int4*)(r1 + koffb + 8);
        int wa[8] = {a0.x, a0.y, a0.z, a0.w, a1.x, a1.y, a1.z, a1.w};
        int wb[8] = {b0.x, b0.y, b0.z, b0.w, b1.x, b1.y, b1.z, b1.w};
        #pragma unroll
        for (int i = 0; i < 8; ++i) {
            unsigned ua = (unsigned)wa[i], ub = (unsigned)wb[i];
            k[2*i+0] = bfu(ua & 0xFFFFu) + bfu(ub & 0xFFFFu);
            k[2*i+1] = bfu(ua >> 16)     + bfu(ub >> 16);
        }
        #pragma unroll
        for (int d = 0; d < 16; ++d) sk += k[d] * k[d];
    }
    float rk = rsqrtf(sk * (1.f / 16.f) + 1e-6f);

    // logit = k̂·q̂ / 4 + b
    float logit = 0.f;
    #pragma unroll
    for (int d = 0; d < 16; ++d) logit += (k[d] * rk * snw[16 + d]) * q[d];
    logit = logit * 0.25f + sb[hh * 4 + g];

    // sum over sink tokens
    float accum = 0.f;
    const float* kbh = skb + hh * 256;
    #pragma unroll
    for (int s = 0; s < 16; ++s) {
        float lb = 0.f;
        #pragma unroll
        for (int d = 0; d < 16; ++d) lb += kbh[s * 16 + d] * q[d];
        accum += __expf(lb * 0.25f - logit);
    }
    float r = 1.f / (1.f + accum);

    // mean over g (4 lanes), lane g==0 writes
    r += __shfl_xor(r, 1);
    r += __shfl_xor(r, 2);
    if (g == 0) out[(size_t)hh * NSEQ + tok] = r * 0.25f;
}

// ---- launch ---------------------------------------------------------------
extern "C" void kernel_launch(void* const* d_in, const int* in_sizes, int n_in,
                              void* d_out, int out_size, void* d_ws, size_t ws_size,
                              hipStream_t stream)
{
    const float* hid = (const float*)d_in[0];
    const float* qw  = (const float*)d_in[1];
    const float* qb  = (const float*)d_in[2];
    const float* kw  = (const float*)d_in[3];
    const float* qnw = (const float*)d_in[4];
    const float* knw = (const float*)d_in[5];
    const float* kb  = (const float*)d_in[6];
    const float* bb  = (const float*)d_in[7];
    float* out = (float*)d_out;

    u16* Wst = (u16*)d_ws;                                        // 5,242,880 B
    u16* P0  = (u16*)((char*)d_ws + (size_t)NCOL * KD * 2);       // 20,971,520 B
    u16* P1  = P0 + (size_t)NSEQ * NCOL;                          // 20,971,520 B

    wconv_kernel<<<WCONV_THREADS / 256, 256, 0, stream>>>(qw, kw, Wst);
    gemm_kernel<<<512, 512, 0, stream>>>(hid, Wst, P0, P1);
    gate_kernel<<<NSEQ * 32 / 256, 256, 0, stream>>>(P0, P1, qb, qnw, knw, kb, bb, out);
}

// Round 11
// 154.308 us; speedup vs baseline: 1.3670x; 1.0286x over previous
//
#include <hip/hip_runtime.h>
#include <hip/hip_bf16.h>

typedef __attribute__((ext_vector_type(8))) short bf16x8;
typedef __attribute__((ext_vector_type(4))) float f32x4;
typedef unsigned short u16;

constexpr int NSEQ = 16384;
constexpr int KD   = 4096;
constexpr int NQ   = 512;     // q cols
constexpr int NCOL = 640;     // q (512) + k (128)
constexpr int BM   = 64;
constexpr int BK   = 32;
constexpr int KHALF = 2048;
constexpr int NKS  = KHALF / BK;          // 64 K-steps per block
// Wst layout: [kh(2)][tt(64)][nblk(8)][frag i(5)][lane(64)][e(8)] u16
constexpr int WST_PER_KH = 64 * 8 * 5 * 64 * 8;   // 1,310,720 u16
constexpr int WST_TT     = 8 * 5 * 64 * 8;        // 20480 u16
constexpr int WST_NB     = 5 * 64 * 8;            // 2560 u16
constexpr int WCONV_THREADS = 2 * 64 * 8 * 5 * 64;   // 327,680

// ---- f32 -> bf16 (RTNE) pack helpers -------------------------------------
__device__ __forceinline__ unsigned bf_round(float x) {
    unsigned u = __builtin_bit_cast(unsigned, x);
    unsigned r = u + 0x7FFFu + ((u >> 16) & 1u);
    return r >> 16;
}
__device__ __forceinline__ unsigned pk2(float lo, float hi) {
    return bf_round(lo) | (bf_round(hi) << 16);
}
__device__ __forceinline__ float bfu(unsigned u) {
    return __builtin_bit_cast(float, u << 16);
}

// ---- Kernel 1: W (q_w ++ k_w) f32 -> bf16, per-(step,wave) fragment blocks
// (identical to R8/R10 — proven)
__global__ __launch_bounds__(256) void wconv_kernel(
    const float* __restrict__ qw, const float* __restrict__ kw,
    u16* __restrict__ Wst)
{
    int g = blockIdx.x * 256 + threadIdx.x;
    int lane = g & 63;
    int r  = g >> 6;
    int i  = r % 5;  r /= 5;
    int nblk = r & 7;  r >>= 3;
    int tt = r & 63;
    int kh = r >> 6;
    int n  = nblk * 80 + i * 16 + (lane & 15);
    int k0 = kh * KHALF + tt * BK + ((lane >> 4) << 3);
    const float* src = (n < NQ) ? (qw + (size_t)n * KD + k0)
                                : (kw + (size_t)(n - NQ) * KD + k0);
    float4 v0 = *(const float4*)(src);
    float4 v1 = *(const float4*)(src + 4);
    int4 o;
    o.x = (int)pk2(v0.x, v0.y);
    o.y = (int)pk2(v0.z, v0.w);
    o.z = (int)pk2(v1.x, v1.y);
    o.w = (int)pk2(v1.z, v1.w);
    *(int4*)(Wst + (size_t)g * 8) = o;
}

// ---- Kernel 2: K-split GEMM, B reg-double-buffered, 2 blocks/CU -----------
// grid 512 = 256 M-blocks x 2 kh; XCD b&7 owns kh (b&7)&1. BM=64, 8 waves,
// wave tile 64 x 80 (acc[4][5] in AGPR). B for step tt+1 is loaded into the
// inactive VGPR set at the TOP of step tt (full-step latency cover; the
// compiler's exact counted vmcnt orders consumption next step). A via 8KB
// LDS dbuf + depth-2 reg rotation. One lgkm(0)+barrier per step.
__global__ __launch_bounds__(512, 4) void gemm_kernel(
    const float* __restrict__ hid, const u16* __restrict__ Wst,
    u16* __restrict__ P0, u16* __restrict__ P1)
{
    __shared__ __align__(16) char smem[2 * 4096];   // A double-buffer, 8 KB

    const int t    = threadIdx.x;
    const int lane = t & 63;
    const int wid  = t >> 6;        // 0..7 = N-slice of 80 cols

    const int b    = blockIdx.x;
    const int xcd  = b & 7;
    const int kh   = xcd & 1;
    const int mblk = (b >> 3) * 4 + (xcd >> 1);   // 0..255, bijective
    const int row0 = mblk * BM;

    const float* hk = hid + (size_t)row0 * KD + kh * KHALF;
    const u16*   wb = Wst + (size_t)kh * WST_PER_KH + wid * WST_NB + lane * 8;
    u16* P = kh ? P1 : P0;

    f32x4 acc[4][5] = {};

    // A staging: thread t -> row ar (0..63), slot ks4 (0..7, 4 f32 each)
    const int ar  = t >> 3;
    const int ks4 = t & 7;
    const float* gA = hk + (size_t)ar * KD + ks4 * 4;
    const int aWoff = ar * 64 + ((((ks4 >> 1) ^ ((ar >> 1) & 3)) << 4)
                                 + (ks4 & 1) * 8);

    // A fragment read params (XOR-swizzled 16B k-slots, 0-conflict proven)
    const int bn   = lane & 15;
    const int koff = (((lane >> 4) ^ ((bn >> 1) & 3)) << 4);

    float4 s0, s1;
    bf16x8 u0, u1, u2, u3, u4;   // B set A (even steps)
    bf16x8 v0, v1, v2, v3, v4;   // B set B (odd steps)

#define BLOAD(TT, X0, X1, X2, X3, X4)                                            \
    {                                                                            \
        const u16* wp_ = wb + (size_t)(TT) * WST_TT;                             \
        X0 = *(const bf16x8*)(wp_);                                              \
        X1 = *(const bf16x8*)(wp_ + 512);                                        \
        X2 = *(const bf16x8*)(wp_ + 1024);                                       \
        X3 = *(const bf16x8*)(wp_ + 1536);                                       \
        X4 = *(const bf16x8*)(wp_ + 2048);                                       \
    }

#define STEPX(TT, CUR, C0, C1, C2, C3, C4, N0, N1, N2, N3, N4, SW, SL, HG, HA, HB) \
    {                                                                            \
        if (HB) BLOAD((TT) + 1, N0, N1, N2, N3, N4);                             \
        if (HA) { SL = *(const float4*)(gA + ((TT) + 2) * BK); }                 \
        if (HG) {                                                                \
            int2 ap_;                                                            \
            ap_.x = (int)pk2(SW.x, SW.y);                                        \
            ap_.y = (int)pk2(SW.z, SW.w);                                        \
            *(int2*)(smem + ((CUR) ^ 1) * 4096 + aWoff) = ap_;                   \
        }                                                                        \
        const char* sAc = smem + (CUR) * 4096;                                   \
        _Pragma("unroll")                                                        \
        for (int m = 0; m < 4; ++m) {                                            \
            bf16x8 a_ = *(const bf16x8*)(sAc + (m * 16 + bn) * 64 + koff);       \
            acc[m][0] = __builtin_amdgcn_mfma_f32_16x16x32_bf16(a_, C0, acc[m][0], 0, 0, 0); \
            acc[m][1] = __builtin_amdgcn_mfma_f32_16x16x32_bf16(a_, C1, acc[m][1], 0, 0, 0); \
            acc[m][2] = __builtin_amdgcn_mfma_f32_16x16x32_bf16(a_, C2, acc[m][2], 0, 0, 0); \
            acc[m][3] = __builtin_amdgcn_mfma_f32_16x16x32_bf16(a_, C3, acc[m][3], 0, 0, 0); \
            acc[m][4] = __builtin_amdgcn_mfma_f32_16x16x32_bf16(a_, C4, acc[m][4], 0, 0, 0); \
        }                                                                        \
        asm volatile("s_waitcnt lgkmcnt(0)" ::: "memory");                       \
        __builtin_amdgcn_s_barrier();                                            \
    }

    // ---- prologue: s0=A(0), s1=A(1); write A(0)->buf0; B(0)->set U ----
    s0 = *(const float4*)(gA);
    s1 = *(const float4*)(gA + BK);
    {
        int2 ap_;
        ap_.x = (int)pk2(s0.x, s0.y);
        ap_.y = (int)pk2(s0.z, s0.w);
        *(int2*)(smem + aWoff) = ap_;
    }
    BLOAD(0, u0, u1, u2, u3, u4);
    asm volatile("s_waitcnt lgkmcnt(0)" ::: "memory");
    __builtin_amdgcn_s_barrier();

    // ---- steady: tt = 0..61 ----
#pragma unroll 1
    for (int t2 = 0; t2 < 31; ++t2) {
        const int tt = t2 * 2;
        STEPX(tt,     0, u0, u1, u2, u3, u4, v0, v1, v2, v3, v4, s1, s0, 1, 1, 1)
        STEPX(tt + 1, 1, v0, v1, v2, v3, v4, u0, u1, u2, u3, u4, s0, s1, 1, 1, 1)
    }
    // ---- tail ----
    STEPX(62, 0, u0, u1, u2, u3, u4, v0, v1, v2, v3, v4, s1, s0, 1, 0, 1)
    STEPX(63, 1, v0, v1, v2, v3, v4, u0, u1, u2, u3, u4, s0, s1, 0, 0, 0)
#undef STEPX
#undef BLOAD

    // epilogue: bf16 partial-P write. C/D: col=lane&15, row=(lane>>4)*4+j
    const int crow = (lane >> 4) << 2;
    const int ccol = lane & 15;
    #pragma unroll
    for (int m = 0; m < 4; ++m)
        #pragma unroll
        for (int f = 0; f < 5; ++f)
            #pragma unroll
            for (int j = 0; j < 4; ++j)
                P[(size_t)(row0 + m * 16 + crow + j) * NCOL
                  + wid * 80 + f * 16 + ccol] = (u16)bf_round(acc[m][f][j]);
}

// ---- Kernel 3: gating epilogue (reads two bf16 partial-P halves) ----------
__global__ __launch_bounds__(256) void gate_kernel(
    const u16* __restrict__ P0, const u16* __restrict__ P1,
    const float* __restrict__ qb,
    const float* __restrict__ qnw, const float* __restrict__ knw,
    const float* __restrict__ kbase, const float* __restrict__ bb,
    float* __restrict__ out)
{
    __shared__ float skb[8 * 16 * 16];
    __shared__ float sqb[512];
    __shared__ float sb[32];
    __shared__ float snw[32];

    int tid = threadIdx.x;
    for (int i = tid; i < 2048; i += 256) skb[i] = kbase[i];
    for (int i = tid; i < 512;  i += 256) sqb[i] = qb[i];
    if (tid < 32) sb[tid] = bb[tid];
    if (tid < 16) snw[tid] = qnw[tid];
    else if (tid < 32) snw[tid] = knw[tid - 16];
    __syncthreads();

    int gid = blockIdx.x * 256 + tid;
    int tok = gid >> 5;
    int hh  = (gid >> 2) & 7;
    int g   = gid & 3;

    const u16* r0 = P0 + (size_t)tok * NCOL;
    const u16* r1 = P1 + (size_t)tok * NCOL;
    const int qoff = (hh * 4 + g) * 16;

    // q row = P0 + P1 + bias, then RMSNorm
    float q[16];
    float ss = 0.f;
    {
        int4 a0 = *(const int4*)(r0 + qoff);
        int4 a1 = *(const int4*)(r0 + qoff + 8);
        int4 b0 = *(const int4*)(r1 + qoff);
        int4 b1 = *(const int4*)(r1 + qoff + 8);
        int wa[8] = {a0.x, a0.y, a0.z, a0.w, a1.x, a1.y, a1.z, a1.w};
        int wb[8] = {b0.x, b0.y, b0.z, b0.w, b1.x, b1.y, b1.z, b1.w};
        #pragma unroll
        for (int i = 0; i < 8; ++i) {
            unsigned ua = (unsigned)wa[i], ub = (unsigned)wb[i];
            q[2*i+0] = bfu(ua & 0xFFFFu) + bfu(ub & 0xFFFFu) + sqb[qoff + 2*i+0];
            q[2*i+1] = bfu(ua >> 16)     + bfu(ub >> 16)     + sqb[qoff + 2*i+1];
        }
        #pragma unroll
        for (int d = 0; d < 16; ++d) ss += q[d] * q[d];
    }
    float rq = rsqrtf(ss * (1.f / 16.f) + 1e-6f);
    #pragma unroll
    for (int d = 0; d < 16; ++d) q[d] *= rq * snw[d];

    // k row, RMSNorm
    float k[16];
    float sk = 0.f;
    {
        const int koffb = NQ + hh * 16;
        int4 a0 = *(const int4*)(r0 + koffb);
        int4 a1 = *(const int4*)(r0 + koffb + 8);
        int4 b0 = *(const int4*)(r1 + koffb);
        int4 b1 = *(const int4*)(r1 + koffb + 8);
        int wa[8] = {a0.x, a0.y, a0.z, a0.w, a1.x, a1.y, a1.z, a1.w};
        int wb[8] = {b0.x, b0.y, b0.z, b0.w, b1.x, b1.y, b1.z, b1.w};
        #pragma unroll
        for (int i = 0; i < 8; ++i) {
            unsigned ua = (unsigned)wa[i], ub = (unsigned)wb[i];
            k[2*i+0] = bfu(ua & 0xFFFFu) + bfu(ub & 0xFFFFu);
            k[2*i+1] = bfu(ua >> 16)     + bfu(ub >> 16);
        }
        #pragma unroll
        for (int d = 0; d < 16; ++d) sk += k[d] * k[d];
    }
    float rk = rsqrtf(sk * (1.f / 16.f) + 1e-6f);

    // logit = k̂·q̂ / 4 + b
    float logit = 0.f;
    #pragma unroll
    for (int d = 0; d < 16; ++d) logit += (k[d] * rk * snw[16 + d]) * q[d];
    logit = logit * 0.25f + sb[hh * 4 + g];

    // sum over sink tokens
    float accum = 0.f;
    const float* kbh = skb + hh * 256;
    #pragma unroll
    for (int s = 0; s < 16; ++s) {
        float lb = 0.f;
        #pragma unroll
        for (int d = 0; d < 16; ++d) lb += kbh[s * 16 + d] * q[d];
        accum += __expf(lb * 0.25f - logit);
    }
    float r = 1.f / (1.f + accum);

    // mean over g (4 lanes), lane g==0 writes
    r += __shfl_xor(r, 1);
    r += __shfl_xor(r, 2);
    if (g == 0) out[(size_t)hh * NSEQ + tok] = r * 0.25f;
}

// ---- launch ---------------------------------------------------------------
extern "C" void kernel_launch(void* const* d_in, const int* in_sizes, int n_in,
                              void* d_out, int out_size, void* d_ws, size_t ws_size,
                              hipStream_t stream)
{
    const float* hid = (const float*)d_in[0];
    const float* qw  = (const float*)d_in[1];
    const float* qb  = (const float*)d_in[2];
    const float* kw  = (const float*)d_in[3];
    const float* qnw = (const float*)d_in[4];
    const float* knw = (const float*)d_in[5];
    const float* kb  = (const float*)d_in[6];
    const float* bb  = (const float*)d_in[7];
    float* out = (float*)d_out;

    u16* Wst = (u16*)d_ws;                                        // 5,242,880 B
    u16* P0  = (u16*)((char*)d_ws + (size_t)NCOL * KD * 2);       // 20,971,520 B
    u16* P1  = P0 + (size_t)NSEQ * NCOL;                          // 20,971,520 B

    wconv_kernel<<<WCONV_THREADS / 256, 256, 0, stream>>>(qw, kw, Wst);
    gemm_kernel<<<512, 512, 0, stream>>>(hid, Wst, P0, P1);
    gate_kernel<<<NSEQ * 32 / 256, 256, 0, stream>>>(P0, P1, qb, qnw, knw, kb, bb, out);
}